// Round 5
// baseline (119.206 us; speedup 1.0000x reference)
//
#include <hip/hip_runtime.h>

#define TEMP 10.0f
#define NS 4096
#define BB 512
#define DDIM 512
#define NCLS 10
#define LDSP 72

typedef short bf16x8 __attribute__((ext_vector_type(8)));
typedef float f32x4 __attribute__((ext_vector_type(4)));

__device__ inline short f2bf(float f) {
    unsigned u = __builtin_bit_cast(unsigned, f);
    u += 0x7FFFu + ((u >> 16) & 1u);      // round-to-nearest-even
    return (short)(u >> 16);
}
__device__ inline float bf2f(short h) {
    unsigned u = ((unsigned)(unsigned short)h) << 16;
    return __builtin_bit_cast(float, u);
}

// =============== prep: all conversions / norms / col0 extraction ===============
// blocks [0,1024)    : star rows -> Sb bf16 + sn2 + scol
// blocks [1024,1152) : x rows    -> Xb bf16 + xn2 + xcol (+ midx init on block 1024)
// blocks [1152,2176) : from rows -> Fb bf16 + fn2
// blocks [2176,2688) : from tiles -> FTb (bf16 transpose [DDIM][NS])
__global__ __launch_bounds__(256)
void prep(const float* __restrict__ x, const float* __restrict__ star,
          const float* __restrict__ from,
          short* __restrict__ Xb, short* __restrict__ Sb,
          short* __restrict__ FTb, short* __restrict__ Fb,
          float* __restrict__ xn2, float* __restrict__ sn2, float* __restrict__ fn2,
          float* __restrict__ scol, float* __restrict__ xcol, int* __restrict__ midx)
{
    int bid = blockIdx.x, t = threadIdx.x;
    if (bid < 2176) {
        const float* in; short* outb; float* n2; float* colb; int rowbase;
        if (bid < 1024)      { in = star; outb = Sb; n2 = sn2; colb = scol; rowbase = bid * 4; }
        else if (bid < 1152) { in = x;    outb = Xb; n2 = xn2; colb = xcol; rowbase = (bid - 1024) * 4; }
        else                 { in = from; outb = Fb; n2 = fn2; colb = nullptr; rowbase = (bid - 1152) * 4; }
        if (bid == 1024) { midx[t] = NS; midx[256 + t] = NS; }
        int row = rowbase + (t >> 6);
        int l = t & 63;
        const float4* p = (const float4*)(in + (size_t)row * DDIM) + l * 2;
        float4 a = p[0], b = p[1];
        float s = a.x*a.x + a.y*a.y + a.z*a.z + a.w*a.w
                + b.x*b.x + b.y*b.y + b.z*b.z + b.w*b.w;
        bf16x8 h;
        h[0]=f2bf(a.x); h[1]=f2bf(a.y); h[2]=f2bf(a.z); h[3]=f2bf(a.w);
        h[4]=f2bf(b.x); h[5]=f2bf(b.y); h[6]=f2bf(b.z); h[7]=f2bf(b.w);
        *(bf16x8*)(outb + (size_t)row * DDIM + l * 8) = h;
        #pragma unroll
        for (int off = 32; off > 0; off >>= 1) s += __shfl_down(s, off);
        if (l == 0) {
            n2[row] = s;
            if (colb) colb[row] = a.x;
        }
        return;
    }
    // ---- from transpose tile ----
    __shared__ short tile[64][LDSP];
    int tid2 = bid - 2176;
    int n0 = (tid2 & 63) * 64, d0 = (tid2 >> 6) * 64;
    int r = t >> 4, c4 = (t & 15) * 4;
    #pragma unroll
    for (int rr = 0; rr < 64; rr += 16) {
        float4 v = *(const float4*)(from + (size_t)(n0 + r + rr) * DDIM + d0 + c4);
        tile[r + rr][c4 + 0] = f2bf(v.x);
        tile[r + rr][c4 + 1] = f2bf(v.y);
        tile[r + rr][c4 + 2] = f2bf(v.z);
        tile[r + rr][c4 + 3] = f2bf(v.w);
    }
    __syncthreads();
    int dr = t >> 2, nco = (t & 3) * 16;
    short tmp[16];
    #pragma unroll
    for (int q = 0; q < 16; ++q) tmp[q] = tile[nco + q][dr];
    short* op = FTb + (size_t)(d0 + dr) * NS + n0 + nco;
    *(bf16x8*)op       = *(bf16x8*)tmp;
    *(bf16x8*)(op + 8) = *(bf16x8*)(tmp + 8);
}

// =============== exact-match scan (col0 prefilter), 8 blocks ===============
__global__ __launch_bounds__(256)
void match8(const float* __restrict__ x, const float* __restrict__ star,
            const float* __restrict__ scol, const float* __restrict__ xcol,
            int* __restrict__ midx)
{
    __shared__ float xl[BB];
    int t = threadIdx.x;
    xl[t] = xcol[t]; xl[256 + t] = xcol[256 + t];
    __syncthreads();
    #pragma unroll
    for (int rep = 0; rep < 2; ++rep) {
        int n = blockIdx.x * 512 + rep * 256 + t;
        float sv = scol[n];
        for (int b = 0; b < BB; ++b) {
            if (xl[b] == sv) {
                const float* xr = x + (size_t)b * DDIM;
                const float* sr = star + (size_t)n * DDIM;
                bool eq = true;
                for (int k = 0; k < DDIM && eq; k += 4) {
                    float4 xv = *(const float4*)(xr + k);
                    float4 s4 = *(const float4*)(sr + k);
                    eq = (xv.x == s4.x) && (xv.y == s4.y) &&
                         (xv.z == s4.z) && (xv.w == s4.w);
                }
                if (eq) atomicMin(&midx[b], n);
            }
        }
    }
}

// =============== MFMA GEMM partials: C[z][m][n] = sum_{k in slab z} A[m][k]*B[n][k] ====
// Round-3-proven body: BM=64, BN=128, BK=64, runtime nt loop, double-buffered LDS,
// 4 waves (2x2), acc 2x4 fragments/wave. Grid (M/64, N/128, nz), kslab = K/nz.
__global__ __launch_bounds__(256)
void gemm_bt(const short* __restrict__ A, const short* __restrict__ B, int K,
             int kslab, int nt, float* __restrict__ C, int ldc, size_t cstride)
{
    __shared__ short As[2][64][LDSP];    // 18432 B
    __shared__ short Bs[2][128][LDSP];   // 36864 B
    int t = threadIdx.x;
    int m0 = blockIdx.x * 64;
    int n0 = blockIdx.y * 128;
    int kbase = blockIdx.z * kslab;
    float* Cp = C + (size_t)blockIdx.z * cstride;
    int wid = t >> 6, lane = t & 63;
    int wr = wid >> 1, wc = wid & 1;
    int lr = lane & 15, lk = lane >> 4;

    int ar = t >> 2, ak = (t & 3) * 16;
    int br = t >> 1, bk = (t & 1) * 32;
    const short* Ag = A + (size_t)(m0 + ar) * K + kbase + ak;
    const short* Bg = B + (size_t)(n0 + br) * K + kbase + bk;

    f32x4 acc[2][4] = {};
    bf16x8 ra0 = *(const bf16x8*)Ag;
    bf16x8 ra1 = *(const bf16x8*)(Ag + 8);
    bf16x8 rb0 = *(const bf16x8*)Bg;
    bf16x8 rb1 = *(const bf16x8*)(Bg + 8);
    bf16x8 rb2 = *(const bf16x8*)(Bg + 16);
    bf16x8 rb3 = *(const bf16x8*)(Bg + 24);
    int cur = 0;
    *(bf16x8*)&As[0][ar][ak]      = ra0;
    *(bf16x8*)&As[0][ar][ak + 8]  = ra1;
    *(bf16x8*)&Bs[0][br][bk]      = rb0;
    *(bf16x8*)&Bs[0][br][bk + 8]  = rb1;
    *(bf16x8*)&Bs[0][br][bk + 16] = rb2;
    *(bf16x8*)&Bs[0][br][bk + 24] = rb3;

    for (int it = 0; it < nt; ++it) {
        __syncthreads();
        if (it + 1 < nt) {
            int ko = (it + 1) * 64;
            ra0 = *(const bf16x8*)(Ag + ko);
            ra1 = *(const bf16x8*)(Ag + ko + 8);
            rb0 = *(const bf16x8*)(Bg + ko);
            rb1 = *(const bf16x8*)(Bg + ko + 8);
            rb2 = *(const bf16x8*)(Bg + ko + 16);
            rb3 = *(const bf16x8*)(Bg + ko + 24);
        }
        #pragma unroll
        for (int ks = 0; ks < 2; ++ks) {
            int k0 = ks * 32 + lk * 8;
            bf16x8 af[2], bfr[4];
            #pragma unroll
            for (int i = 0; i < 2; ++i)
                af[i] = *(const bf16x8*)&As[cur][wr * 32 + i * 16 + lr][k0];
            #pragma unroll
            for (int j = 0; j < 4; ++j)
                bfr[j] = *(const bf16x8*)&Bs[cur][wc * 64 + j * 16 + lr][k0];
            #pragma unroll
            for (int i = 0; i < 2; ++i)
                #pragma unroll
                for (int j = 0; j < 4; ++j)
                    acc[i][j] = __builtin_amdgcn_mfma_f32_16x16x32_bf16(
                        af[i], bfr[j], acc[i][j], 0, 0, 0);
        }
        if (it + 1 < nt) {
            cur ^= 1;
            *(bf16x8*)&As[cur][ar][ak]      = ra0;
            *(bf16x8*)&As[cur][ar][ak + 8]  = ra1;
            *(bf16x8*)&Bs[cur][br][bk]      = rb0;
            *(bf16x8*)&Bs[cur][br][bk + 8]  = rb1;
            *(bf16x8*)&Bs[cur][br][bk + 16] = rb2;
            *(bf16x8*)&Bs[cur][br][bk + 24] = rb3;
        }
    }
    #pragma unroll
    for (int i = 0; i < 2; ++i) {
        #pragma unroll
        for (int r = 0; r < 4; ++r) {
            int gm = m0 + wr * 32 + i * 16 + lk * 4 + r;
            #pragma unroll
            for (int j = 0; j < 4; ++j) {
                int gn = n0 + wc * 64 + j * 16 + lr;
                Cp[(size_t)gm * ldc + gn] = acc[i][j][r];
            }
        }
    }
}

// =============== block-wide sum helper ===============
__device__ inline float block_sum(float s, float* red) {
    #pragma unroll
    for (int off = 32; off > 0; off >>= 1) s += __shfl_down(s, off);
    int wid = threadIdx.x >> 6;
    if ((threadIdx.x & 63) == 0) red[wid] = s;
    __syncthreads();
    float tot = red[0] + red[1] + red[2] + red[3];
    __syncthreads();
    return tot;
}

// === finish sqdist from 2 dot-partials, softmax over row -> bf16 eT + sumE ===
__global__ __launch_bounds__(256)
void exp_sq(const float* __restrict__ dTp, const float* __restrict__ an2,
            const float* __restrict__ bn2, short* __restrict__ eT,
            float* __restrict__ sumE)
{
    __shared__ float red[4];
    int b = blockIdx.x;
    int t = threadIdx.x;
    const float* p0 = dTp + (size_t)b * NS;
    const float* p1 = p0 + (size_t)BB * NS;
    float a2 = an2[b];
    float v[16];
    float s = 0.f;
    #pragma unroll
    for (int q = 0; q < 4; ++q) {
        int n = t * 16 + q * 4;
        float4 u0 = *(const float4*)(p0 + n);
        float4 u1 = *(const float4*)(p1 + n);
        float4 n2 = *(const float4*)(bn2 + n);
        float4 w;
        w.x = fmaxf(a2 + n2.x - 2.0f * (u0.x + u1.x), 0.f);
        w.y = fmaxf(a2 + n2.y - 2.0f * (u0.y + u1.y), 0.f);
        w.z = fmaxf(a2 + n2.z - 2.0f * (u0.z + u1.z), 0.f);
        w.w = fmaxf(a2 + n2.w - 2.0f * (u0.w + u1.w), 0.f);
        v[q*4+0] = w.x; v[q*4+1] = w.y; v[q*4+2] = w.z; v[q*4+3] = w.w;
        s += w.x + w.y + w.z + w.w;
    }
    float tot = block_sum(s, red);
    float scale = -TEMP * (float)NS / tot;
    float se = 0.f;
    bf16x8 h0, h1;
    #pragma unroll
    for (int e = 0; e < 16; ++e) {
        float ev = __expf(v[e] * scale);
        short hh = f2bf(ev);
        se += bf2f(hh);
        if (e < 8) h0[e] = hh; else h1[e - 8] = hh;
    }
    short* op = eT + (size_t)b * NS + t * 16;
    *(bf16x8*)op       = h0;
    *(bf16x8*)(op + 8) = h1;
    float setot = block_sum(se, red);
    if (t == 0) sumE[b] = setot;
}

// === xt = (sum of 16 w-slabs)/sumE (or matched row) -> bf16 + norm ===
__global__ __launch_bounds__(256)
void xt_fin(const float* __restrict__ wpart, const float* __restrict__ sumE,
            const int* __restrict__ midx, const float* __restrict__ fromf,
            short* __restrict__ xtb, float* __restrict__ xtn2)
{
    __shared__ float red[4];
    int b = blockIdx.x;
    int t = threadIdx.x;
    int d = t * 2;
    int mi = midx[b];
    float inv = 1.0f / sumE[b];
    float v0 = 0.f, v1 = 0.f;
    #pragma unroll
    for (int sl = 0; sl < 16; ++sl) {
        float2 p = *(const float2*)(wpart + (size_t)sl * (BB * DDIM) + (size_t)b * DDIM + d);
        v0 += p.x; v1 += p.y;
    }
    v0 *= inv; v1 *= inv;
    if (mi < NS) {
        v0 = fromf[(size_t)mi * DDIM + d];
        v1 = fromf[(size_t)mi * DDIM + d + 1];
    }
    xtb[(size_t)b * DDIM + d]     = f2bf(v0);
    xtb[(size_t)b * DDIM + d + 1] = f2bf(v1);
    float tot = block_sum(v0 * v0 + v1 * v1, red);
    if (t == 0) xtn2[b] = tot;
}

// === y_star row: finish sqdist from 2 partials, softmax-weighted one-hot avg ===
__global__ __launch_bounds__(256)
void ystar_sq(const float* __restrict__ d2p, const float* __restrict__ an2,
              const float* __restrict__ bn2, const int* __restrict__ labels,
              float* __restrict__ out)
{
    __shared__ float red[4];
    __shared__ float cred[NCLS + 1][4];
    int b = blockIdx.x;
    int t = threadIdx.x;
    const float* p0 = d2p + (size_t)b * NS;
    const float* p1 = p0 + (size_t)BB * NS;
    float a2 = an2[b];
    float v[16];
    float s = 0.f;
    #pragma unroll
    for (int q = 0; q < 4; ++q) {
        int n = t * 16 + q * 4;
        float4 u0 = *(const float4*)(p0 + n);
        float4 u1 = *(const float4*)(p1 + n);
        float4 n2 = *(const float4*)(bn2 + n);
        float4 w;
        w.x = fmaxf(a2 + n2.x - 2.0f * (u0.x + u1.x), 0.f);
        w.y = fmaxf(a2 + n2.y - 2.0f * (u0.y + u1.y), 0.f);
        w.z = fmaxf(a2 + n2.z - 2.0f * (u0.z + u1.z), 0.f);
        w.w = fmaxf(a2 + n2.w - 2.0f * (u0.w + u1.w), 0.f);
        v[q*4+0] = w.x; v[q*4+1] = w.y; v[q*4+2] = w.z; v[q*4+3] = w.w;
        s += w.x + w.y + w.z + w.w;
    }
    float tot = block_sum(s, red);
    float scale = -TEMP * (float)NS / tot;
    float accs[NCLS] = {};
    float te = 0.f;
    #pragma unroll
    for (int q = 0; q < 4; ++q) {
        int4 lb = *(const int4*)(labels + t * 16 + q * 4);
        int lbl[4] = {lb.x, lb.y, lb.z, lb.w};
        #pragma unroll
        for (int e = 0; e < 4; ++e) {
            float ev = __expf(v[q * 4 + e] * scale);
            te += ev;
            #pragma unroll
            for (int c = 0; c < NCLS; ++c) accs[c] += (lbl[e] == c) ? ev : 0.f;
        }
    }
    int wid = t >> 6, lane = t & 63;
    #pragma unroll
    for (int c = 0; c < NCLS + 1; ++c) {
        float sv = (c < NCLS) ? accs[c] : te;
        #pragma unroll
        for (int off = 32; off > 0; off >>= 1) sv += __shfl_down(sv, off);
        if (lane == 0) cred[c][wid] = sv;
    }
    __syncthreads();
    if (t < NCLS) {
        float num = cred[t][0] + cred[t][1] + cred[t][2] + cred[t][3];
        float den = cred[NCLS][0] + cred[NCLS][1] + cred[NCLS][2] + cred[NCLS][3];
        out[b * NCLS + t] = num / den;
    }
}

extern "C" void kernel_launch(void* const* d_in, const int* in_sizes, int n_in,
                              void* d_out, int out_size, void* d_ws, size_t ws_size,
                              hipStream_t stream) {
    const float* x     = (const float*)d_in[0];
    const float* star  = (const float*)d_in[1];
    const float* from  = (const float*)d_in[2];
    const int*   label = (const int*)d_in[3];
    float* out = (float*)d_out;

    float* F = (float*)d_ws;                    // uses ~68 MB of workspace
    float* dTp   = F;                           // 2 x [512][4096] f32 (16 MB)
    float* wpart = F + 4194304;                 // 16 x [512][512] f32 (16 MB)
    float* d2p   = F + 8388608;                 // 2 x [512][4096] f32 (16 MB)
    short* Sb    = (short*)(F + 12582912);      // star bf16  [4096][512] (4 MB)
    short* FTb   = (short*)(F + 13631488);      // fromT bf16 [512][4096] (4 MB)
    short* Fb    = (short*)(F + 14680064);      // from bf16  [4096][512] (4 MB)
    short* Eb    = (short*)(F + 15728640);      // eT bf16    [512][4096] (4 MB)
    short* Xb    = (short*)(F + 16777216);      // x bf16     [512][512]
    short* XTb   = (short*)(F + 16908288);      // xt bf16    [512][512]
    float* sn2   = F + 17039360;                // 4096
    float* fn2   = F + 17043456;                // 4096
    float* xn2   = F + 17047552;                // 512
    float* xtn2  = F + 17048064;                // 512
    float* sumE  = F + 17048576;                // 512
    float* scol  = F + 17049088;                // 4096
    float* xcol  = F + 17053184;                // 512
    int*   midx  = (int*)(F + 17053696);        // 512

    prep<<<2688, 256, 0, stream>>>(x, star, from, Xb, Sb, FTb, Fb,
                                   xn2, sn2, fn2, scol, xcol, midx);
    match8<<<8, 256, 0, stream>>>(x, star, scol, xcol, midx);
    // dot partials: dTp[z][b][n] = sum_{k in slab z} x[b][k]*star[n][k]
    gemm_bt<<<dim3(8, 32, 2), 256, 0, stream>>>(Xb, Sb, DDIM, 256, 4, dTp, NS,
                                                (size_t)BB * NS);
    exp_sq<<<BB, 256, 0, stream>>>(dTp, xn2, sn2, Eb, sumE);
    // wpart[z][b][d] = sum_{n in slab z} eT[b][n]*fromT[d][n]
    gemm_bt<<<dim3(8, 4, 16), 256, 0, stream>>>(Eb, FTb, NS, 256, 4, wpart, DDIM,
                                                (size_t)BB * DDIM);
    xt_fin<<<BB, 256, 0, stream>>>(wpart, sumE, midx, from, XTb, xtn2);
    // d2 dot partials
    gemm_bt<<<dim3(8, 32, 2), 256, 0, stream>>>(XTb, Fb, DDIM, 256, 4, d2p, NS,
                                                (size_t)BB * NS);
    ystar_sq<<<BB, 256, 0, stream>>>(d2p, xtn2, fn2, label, out);
}

// Round 6
// 76.034 us; speedup vs baseline: 1.5678x; 1.5678x over previous
//
#include <hip/hip_runtime.h>

#define TEMP 10.0f
#define NS 4096
#define BB 512
#define DDIM 512
#define NCLS 10
#define LDSP 72

typedef short bf16x8 __attribute__((ext_vector_type(8)));
typedef float f32x4 __attribute__((ext_vector_type(4)));

__device__ inline short f2bf(float f) {
    unsigned u = __builtin_bit_cast(unsigned, f);
    u += 0x7FFFu + ((u >> 16) & 1u);      // round-to-nearest-even
    return (short)(u >> 16);
}
__device__ inline float bf2f(short h) {
    unsigned u = ((unsigned)(unsigned short)h) << 16;
    return __builtin_bit_cast(float, u);
}

// =============== prep: all conversions / norms / col0 extraction ===============
// blocks [0,1024)    : star rows -> Sb bf16 + sn2 + scol
// blocks [1024,1152) : x rows    -> Xb bf16 + xn2 + xcol (+ midx init on block 1024)
// blocks [1152,2176) : from rows -> Fb bf16 + fn2
// blocks [2176,2688) : from tiles -> FTb (bf16 transpose [DDIM][NS])
__global__ __launch_bounds__(256)
void prep(const float* __restrict__ x, const float* __restrict__ star,
          const float* __restrict__ from,
          short* __restrict__ Xb, short* __restrict__ Sb,
          short* __restrict__ FTb, short* __restrict__ Fb,
          float* __restrict__ xn2, float* __restrict__ sn2, float* __restrict__ fn2,
          float* __restrict__ scol, float* __restrict__ xcol, int* __restrict__ midx)
{
    int bid = blockIdx.x, t = threadIdx.x;
    if (bid < 2176) {
        const float* in; short* outb; float* n2; float* colb; int rowbase;
        if (bid < 1024)      { in = star; outb = Sb; n2 = sn2; colb = scol; rowbase = bid * 4; }
        else if (bid < 1152) { in = x;    outb = Xb; n2 = xn2; colb = xcol; rowbase = (bid - 1024) * 4; }
        else                 { in = from; outb = Fb; n2 = fn2; colb = nullptr; rowbase = (bid - 1152) * 4; }
        if (bid == 1024) { midx[t] = NS; midx[256 + t] = NS; }
        int row = rowbase + (t >> 6);
        int l = t & 63;
        const float4* p = (const float4*)(in + (size_t)row * DDIM) + l * 2;
        float4 a = p[0], b = p[1];
        float s = a.x*a.x + a.y*a.y + a.z*a.z + a.w*a.w
                + b.x*b.x + b.y*b.y + b.z*b.z + b.w*b.w;
        bf16x8 h;
        h[0]=f2bf(a.x); h[1]=f2bf(a.y); h[2]=f2bf(a.z); h[3]=f2bf(a.w);
        h[4]=f2bf(b.x); h[5]=f2bf(b.y); h[6]=f2bf(b.z); h[7]=f2bf(b.w);
        *(bf16x8*)(outb + (size_t)row * DDIM + l * 8) = h;
        #pragma unroll
        for (int off = 32; off > 0; off >>= 1) s += __shfl_down(s, off);
        if (l == 0) {
            n2[row] = s;
            if (colb) colb[row] = a.x;
        }
        return;
    }
    // ---- from transpose tile ----
    __shared__ short tile[64][LDSP];
    int tid2 = bid - 2176;
    int n0 = (tid2 & 63) * 64, d0 = (tid2 >> 6) * 64;
    int r = t >> 4, c4 = (t & 15) * 4;
    #pragma unroll
    for (int rr = 0; rr < 64; rr += 16) {
        float4 v = *(const float4*)(from + (size_t)(n0 + r + rr) * DDIM + d0 + c4);
        tile[r + rr][c4 + 0] = f2bf(v.x);
        tile[r + rr][c4 + 1] = f2bf(v.y);
        tile[r + rr][c4 + 2] = f2bf(v.z);
        tile[r + rr][c4 + 3] = f2bf(v.w);
    }
    __syncthreads();
    int dr = t >> 2, nco = (t & 3) * 16;
    short tmp[16];
    #pragma unroll
    for (int q = 0; q < 16; ++q) tmp[q] = tile[nco + q][dr];
    short* op = FTb + (size_t)(d0 + dr) * NS + n0 + nco;
    *(bf16x8*)op       = *(bf16x8*)tmp;
    *(bf16x8*)(op + 8) = *(bf16x8*)(tmp + 8);
}

// =============== exact-match scan: 16 blocks, one thread per star row ===============
// Batched float4 LDS reads (unrolled x4 -> 16 independent loads in flight) replace
// the latency-serialized scalar loop that cost 61 us in round 5.
__global__ __launch_bounds__(256)
void match16(const float* __restrict__ x, const float* __restrict__ star,
             const float* __restrict__ scol, const float* __restrict__ xcol,
             int* __restrict__ midx)
{
    __shared__ float xl[BB];
    int t = threadIdx.x;
    *(float2*)&xl[t * 2] = *(const float2*)&xcol[t * 2];
    __syncthreads();
    int n = blockIdx.x * 256 + t;
    float sv = scol[n];
    #pragma unroll 4
    for (int b4 = 0; b4 < BB; b4 += 4) {
        float4 xv = *(const float4*)&xl[b4];
        if (xv.x == sv || xv.y == sv || xv.z == sv || xv.w == sv) {
            #pragma unroll
            for (int j = 0; j < 4; ++j) {
                int b = b4 + j;
                if (xl[b] == sv) {
                    const float* xr = x + (size_t)b * DDIM;
                    const float* sr = star + (size_t)n * DDIM;
                    bool eq = true;
                    for (int k = 0; k < DDIM && eq; k += 4) {
                        float4 a = *(const float4*)(xr + k);
                        float4 c = *(const float4*)(sr + k);
                        eq = (a.x == c.x) && (a.y == c.y) &&
                             (a.z == c.z) && (a.w == c.w);
                    }
                    if (eq) atomicMin(&midx[b], n);
                }
            }
        }
    }
}

// =============== MFMA GEMM partials: C[z][m][n] = sum_{k in slab z} A[m][k]*B[n][k] ====
// BM=64, BN=128, BK=64, runtime nt loop, double-buffered LDS, 4 waves (2x2),
// acc 2x4 fragments/wave. Grid (M/64, N/128, nz), kslab = K/nz.
__global__ __launch_bounds__(256)
void gemm_bt(const short* __restrict__ A, const short* __restrict__ B, int K,
             int kslab, int nt, float* __restrict__ C, int ldc, size_t cstride)
{
    __shared__ short As[2][64][LDSP];    // 18432 B
    __shared__ short Bs[2][128][LDSP];   // 36864 B
    int t = threadIdx.x;
    int m0 = blockIdx.x * 64;
    int n0 = blockIdx.y * 128;
    int kbase = blockIdx.z * kslab;
    float* Cp = C + (size_t)blockIdx.z * cstride;
    int wid = t >> 6, lane = t & 63;
    int wr = wid >> 1, wc = wid & 1;
    int lr = lane & 15, lk = lane >> 4;

    int ar = t >> 2, ak = (t & 3) * 16;
    int br = t >> 1, bk = (t & 1) * 32;
    const short* Ag = A + (size_t)(m0 + ar) * K + kbase + ak;
    const short* Bg = B + (size_t)(n0 + br) * K + kbase + bk;

    f32x4 acc[2][4] = {};
    bf16x8 ra0 = *(const bf16x8*)Ag;
    bf16x8 ra1 = *(const bf16x8*)(Ag + 8);
    bf16x8 rb0 = *(const bf16x8*)Bg;
    bf16x8 rb1 = *(const bf16x8*)(Bg + 8);
    bf16x8 rb2 = *(const bf16x8*)(Bg + 16);
    bf16x8 rb3 = *(const bf16x8*)(Bg + 24);
    int cur = 0;
    *(bf16x8*)&As[0][ar][ak]      = ra0;
    *(bf16x8*)&As[0][ar][ak + 8]  = ra1;
    *(bf16x8*)&Bs[0][br][bk]      = rb0;
    *(bf16x8*)&Bs[0][br][bk + 8]  = rb1;
    *(bf16x8*)&Bs[0][br][bk + 16] = rb2;
    *(bf16x8*)&Bs[0][br][bk + 24] = rb3;

    for (int it = 0; it < nt; ++it) {
        __syncthreads();
        if (it + 1 < nt) {
            int ko = (it + 1) * 64;
            ra0 = *(const bf16x8*)(Ag + ko);
            ra1 = *(const bf16x8*)(Ag + ko + 8);
            rb0 = *(const bf16x8*)(Bg + ko);
            rb1 = *(const bf16x8*)(Bg + ko + 8);
            rb2 = *(const bf16x8*)(Bg + ko + 16);
            rb3 = *(const bf16x8*)(Bg + ko + 24);
        }
        #pragma unroll
        for (int ks = 0; ks < 2; ++ks) {
            int k0 = ks * 32 + lk * 8;
            bf16x8 af[2], bfr[4];
            #pragma unroll
            for (int i = 0; i < 2; ++i)
                af[i] = *(const bf16x8*)&As[cur][wr * 32 + i * 16 + lr][k0];
            #pragma unroll
            for (int j = 0; j < 4; ++j)
                bfr[j] = *(const bf16x8*)&Bs[cur][wc * 64 + j * 16 + lr][k0];
            #pragma unroll
            for (int i = 0; i < 2; ++i)
                #pragma unroll
                for (int j = 0; j < 4; ++j)
                    acc[i][j] = __builtin_amdgcn_mfma_f32_16x16x32_bf16(
                        af[i], bfr[j], acc[i][j], 0, 0, 0);
        }
        if (it + 1 < nt) {
            cur ^= 1;
            *(bf16x8*)&As[cur][ar][ak]      = ra0;
            *(bf16x8*)&As[cur][ar][ak + 8]  = ra1;
            *(bf16x8*)&Bs[cur][br][bk]      = rb0;
            *(bf16x8*)&Bs[cur][br][bk + 8]  = rb1;
            *(bf16x8*)&Bs[cur][br][bk + 16] = rb2;
            *(bf16x8*)&Bs[cur][br][bk + 24] = rb3;
        }
    }
    #pragma unroll
    for (int i = 0; i < 2; ++i) {
        #pragma unroll
        for (int r = 0; r < 4; ++r) {
            int gm = m0 + wr * 32 + i * 16 + lk * 4 + r;
            #pragma unroll
            for (int j = 0; j < 4; ++j) {
                int gn = n0 + wc * 64 + j * 16 + lr;
                Cp[(size_t)gm * ldc + gn] = acc[i][j][r];
            }
        }
    }
}

// =============== block-wide sum helper ===============
__device__ inline float block_sum(float s, float* red) {
    #pragma unroll
    for (int off = 32; off > 0; off >>= 1) s += __shfl_down(s, off);
    int wid = threadIdx.x >> 6;
    if ((threadIdx.x & 63) == 0) red[wid] = s;
    __syncthreads();
    float tot = red[0] + red[1] + red[2] + red[3];
    __syncthreads();
    return tot;
}

// === finish sqdist from 2 dot-partials, softmax over row -> bf16 eT + sumE ===
__global__ __launch_bounds__(256)
void exp_sq(const float* __restrict__ dTp, const float* __restrict__ an2,
            const float* __restrict__ bn2, short* __restrict__ eT,
            float* __restrict__ sumE)
{
    __shared__ float red[4];
    int b = blockIdx.x;
    int t = threadIdx.x;
    const float* p0 = dTp + (size_t)b * NS;
    const float* p1 = p0 + (size_t)BB * NS;
    float a2 = an2[b];
    float v[16];
    float s = 0.f;
    #pragma unroll
    for (int q = 0; q < 4; ++q) {
        int n = t * 16 + q * 4;
        float4 u0 = *(const float4*)(p0 + n);
        float4 u1 = *(const float4*)(p1 + n);
        float4 n2 = *(const float4*)(bn2 + n);
        float4 w;
        w.x = fmaxf(a2 + n2.x - 2.0f * (u0.x + u1.x), 0.f);
        w.y = fmaxf(a2 + n2.y - 2.0f * (u0.y + u1.y), 0.f);
        w.z = fmaxf(a2 + n2.z - 2.0f * (u0.z + u1.z), 0.f);
        w.w = fmaxf(a2 + n2.w - 2.0f * (u0.w + u1.w), 0.f);
        v[q*4+0] = w.x; v[q*4+1] = w.y; v[q*4+2] = w.z; v[q*4+3] = w.w;
        s += w.x + w.y + w.z + w.w;
    }
    float tot = block_sum(s, red);
    float scale = -TEMP * (float)NS / tot;
    float se = 0.f;
    bf16x8 h0, h1;
    #pragma unroll
    for (int e = 0; e < 16; ++e) {
        float ev = __expf(v[e] * scale);
        short hh = f2bf(ev);
        se += bf2f(hh);
        if (e < 8) h0[e] = hh; else h1[e - 8] = hh;
    }
    short* op = eT + (size_t)b * NS + t * 16;
    *(bf16x8*)op       = h0;
    *(bf16x8*)(op + 8) = h1;
    float setot = block_sum(se, red);
    if (t == 0) sumE[b] = setot;
}

// === xt = (sum of 16 w-slabs)/sumE (or matched row) -> bf16 + norm ===
__global__ __launch_bounds__(256)
void xt_fin(const float* __restrict__ wpart, const float* __restrict__ sumE,
            const int* __restrict__ midx, const float* __restrict__ fromf,
            short* __restrict__ xtb, float* __restrict__ xtn2)
{
    __shared__ float red[4];
    int b = blockIdx.x;
    int t = threadIdx.x;
    int d = t * 2;
    int mi = midx[b];
    float inv = 1.0f / sumE[b];
    float v0 = 0.f, v1 = 0.f;
    #pragma unroll
    for (int sl = 0; sl < 16; ++sl) {
        float2 p = *(const float2*)(wpart + (size_t)sl * (BB * DDIM) + (size_t)b * DDIM + d);
        v0 += p.x; v1 += p.y;
    }
    v0 *= inv; v1 *= inv;
    if (mi < NS) {
        v0 = fromf[(size_t)mi * DDIM + d];
        v1 = fromf[(size_t)mi * DDIM + d + 1];
    }
    xtb[(size_t)b * DDIM + d]     = f2bf(v0);
    xtb[(size_t)b * DDIM + d + 1] = f2bf(v1);
    float tot = block_sum(v0 * v0 + v1 * v1, red);
    if (t == 0) xtn2[b] = tot;
}

// === y_star row: finish sqdist from 2 partials, softmax-weighted one-hot avg ===
__global__ __launch_bounds__(256)
void ystar_sq(const float* __restrict__ d2p, const float* __restrict__ an2,
              const float* __restrict__ bn2, const int* __restrict__ labels,
              float* __restrict__ out)
{
    __shared__ float red[4];
    __shared__ float cred[NCLS + 1][4];
    int b = blockIdx.x;
    int t = threadIdx.x;
    const float* p0 = d2p + (size_t)b * NS;
    const float* p1 = p0 + (size_t)BB * NS;
    float a2 = an2[b];
    float v[16];
    float s = 0.f;
    #pragma unroll
    for (int q = 0; q < 4; ++q) {
        int n = t * 16 + q * 4;
        float4 u0 = *(const float4*)(p0 + n);
        float4 u1 = *(const float4*)(p1 + n);
        float4 n2 = *(const float4*)(bn2 + n);
        float4 w;
        w.x = fmaxf(a2 + n2.x - 2.0f * (u0.x + u1.x), 0.f);
        w.y = fmaxf(a2 + n2.y - 2.0f * (u0.y + u1.y), 0.f);
        w.z = fmaxf(a2 + n2.z - 2.0f * (u0.z + u1.z), 0.f);
        w.w = fmaxf(a2 + n2.w - 2.0f * (u0.w + u1.w), 0.f);
        v[q*4+0] = w.x; v[q*4+1] = w.y; v[q*4+2] = w.z; v[q*4+3] = w.w;
        s += w.x + w.y + w.z + w.w;
    }
    float tot = block_sum(s, red);
    float scale = -TEMP * (float)NS / tot;
    float accs[NCLS] = {};
    float te = 0.f;
    #pragma unroll
    for (int q = 0; q < 4; ++q) {
        int4 lb = *(const int4*)(labels + t * 16 + q * 4);
        int lbl[4] = {lb.x, lb.y, lb.z, lb.w};
        #pragma unroll
        for (int e = 0; e < 4; ++e) {
            float ev = __expf(v[q * 4 + e] * scale);
            te += ev;
            #pragma unroll
            for (int c = 0; c < NCLS; ++c) accs[c] += (lbl[e] == c) ? ev : 0.f;
        }
    }
    int wid = t >> 6, lane = t & 63;
    #pragma unroll
    for (int c = 0; c < NCLS + 1; ++c) {
        float sv = (c < NCLS) ? accs[c] : te;
        #pragma unroll
        for (int off = 32; off > 0; off >>= 1) sv += __shfl_down(sv, off);
        if (lane == 0) cred[c][wid] = sv;
    }
    __syncthreads();
    if (t < NCLS) {
        float num = cred[t][0] + cred[t][1] + cred[t][2] + cred[t][3];
        float den = cred[NCLS][0] + cred[NCLS][1] + cred[NCLS][2] + cred[NCLS][3];
        out[b * NCLS + t] = num / den;
    }
}

extern "C" void kernel_launch(void* const* d_in, const int* in_sizes, int n_in,
                              void* d_out, int out_size, void* d_ws, size_t ws_size,
                              hipStream_t stream) {
    const float* x     = (const float*)d_in[0];
    const float* star  = (const float*)d_in[1];
    const float* from  = (const float*)d_in[2];
    const int*   label = (const int*)d_in[3];
    float* out = (float*)d_out;

    float* F = (float*)d_ws;                    // uses ~68 MB of workspace
    float* dTp   = F;                           // 2 x [512][4096] f32 (16 MB)
    float* wpart = F + 4194304;                 // 16 x [512][512] f32 (16 MB)
    float* d2p   = F + 8388608;                 // 2 x [512][4096] f32 (16 MB)
    short* Sb    = (short*)(F + 12582912);      // star bf16  [4096][512] (4 MB)
    short* FTb   = (short*)(F + 13631488);      // fromT bf16 [512][4096] (4 MB)
    short* Fb    = (short*)(F + 14680064);      // from bf16  [4096][512] (4 MB)
    short* Eb    = (short*)(F + 15728640);      // eT bf16    [512][4096] (4 MB)
    short* Xb    = (short*)(F + 16777216);      // x bf16     [512][512]
    short* XTb   = (short*)(F + 16908288);      // xt bf16    [512][512]
    float* sn2   = F + 17039360;                // 4096
    float* fn2   = F + 17043456;                // 4096
    float* xn2   = F + 17047552;                // 512
    float* xtn2  = F + 17048064;                // 512
    float* sumE  = F + 17048576;                // 512
    float* scol  = F + 17049088;                // 4096
    float* xcol  = F + 17053184;                // 512
    int*   midx  = (int*)(F + 17053696);        // 512

    prep<<<2688, 256, 0, stream>>>(x, star, from, Xb, Sb, FTb, Fb,
                                   xn2, sn2, fn2, scol, xcol, midx);
    match16<<<16, 256, 0, stream>>>(x, star, scol, xcol, midx);
    // dot partials: dTp[z][b][n] = sum_{k in slab z} x[b][k]*star[n][k]
    gemm_bt<<<dim3(8, 32, 2), 256, 0, stream>>>(Xb, Sb, DDIM, 256, 4, dTp, NS,
                                                (size_t)BB * NS);
    exp_sq<<<BB, 256, 0, stream>>>(dTp, xn2, sn2, Eb, sumE);
    // wpart[z][b][d] = sum_{n in slab z} eT[b][n]*fromT[d][n]
    gemm_bt<<<dim3(8, 4, 16), 256, 0, stream>>>(Eb, FTb, NS, 256, 4, wpart, DDIM,
                                                (size_t)BB * DDIM);
    xt_fin<<<BB, 256, 0, stream>>>(wpart, sumE, midx, from, XTb, xtn2);
    // d2 dot partials
    gemm_bt<<<dim3(8, 32, 2), 256, 0, stream>>>(XTb, Fb, DDIM, 256, 4, d2p, NS,
                                                (size_t)BB * NS);
    ystar_sq<<<BB, 256, 0, stream>>>(d2p, xtn2, fn2, label, out);
}